// Round 3
// baseline (223.436 us; speedup 1.0000x reference)
//
#include <hip/hip_runtime.h>
#include <hip/hip_bf16.h>
#include <cstdint>
#include <cstddef>

// Problem constants (fixed by the reference)
#define NCAT   8
#define DIN    64
#define HID    1024
#define NBATCH 256
#define HSEQ   64
#define NTOK   (NBATCH * HSEQ)   // 16384
#define MAXTILES 132             // sum ceil(nb_c/2) <= 128 + 4
#define NWG (4 * MAXTILES)       // 528 = 8 * 66 (clean XCD swizzle, r=0)

typedef __bf16 bf16x8 __attribute__((ext_vector_type(8)));
typedef __bf16 bf16x4 __attribute__((ext_vector_type(4)));
typedef float  f32x4  __attribute__((ext_vector_type(4)));

__device__ __forceinline__ void async16(const void* g, void* l) {
    __builtin_amdgcn_global_load_lds(
        (const __attribute__((address_space(1))) unsigned int*)g,
        (__attribute__((address_space(3))) unsigned int*)l,
        16, 0, 0);
}

// ---------------- setup: counting-sort batches by category, build tile table ----------------
// meta layout (ints): order[256] @0, tileB0[160] @256, tileB1[160] @416,
//                     tileCat[160] @576, ntiles @736
__global__ void setup_kernel(const int* __restrict__ cat, int* __restrict__ meta) {
    __shared__ int scat[NBATCH];
    __shared__ int cnt[NCAT], pfx[NCAT + 1];
    const int tid = threadIdx.x;
    const int c = cat[tid];
    scat[tid] = c;
    if (tid < NCAT) cnt[tid] = 0;
    __syncthreads();
    atomicAdd(&cnt[c], 1);
    __syncthreads();
    if (tid == 0) {
        pfx[0] = 0;
        for (int i = 0; i < NCAT; ++i) pfx[i + 1] = pfx[i] + cnt[i];
    }
    __syncthreads();
    int r = 0;
    for (int b = 0; b < tid; ++b) r += (scat[b] == c);
    meta[pfx[c] + r] = tid;                 // order[]
    __threadfence();
    __syncthreads();
    if (tid == 0) {
        int nt = 0;
        for (int cc = 0; cc < NCAT; ++cc) {
            const int base = pfx[cc], n = cnt[cc];
            for (int j = 0; j < n; j += 2) {
                meta[256 + nt] = meta[base + j];                        // tileB0
                meta[416 + nt] = (j + 1 < n) ? meta[base + j + 1] : -1; // tileB1
                meta[576 + nt] = cc;                                    // tileCat
                ++nt;
            }
        }
        meta[736] = nt;
    }
}

// ---------------- prep kernels ----------------

__global__ void pe_kernel(float* __restrict__ pe) {
    const int t = blockIdx.x;        // 0..63
    const int i = threadIdx.x;       // 0..511
    const float div = expf((float)(2 * i) * (-9.210340371976184f / 1024.f));
    const float a = (float)t * div;
    pe[t * HID + 2 * i]     = sinf(a);
    pe[t * HID + 2 * i + 1] = cosf(a);
}

__global__ void cvt_x_kernel(const float* __restrict__ x, __bf16* __restrict__ xb) {
    const size_t i = (size_t)blockIdx.x * blockDim.x + threadIdx.x;
    const float4 v = ((const float4*)x)[i];
    bf16x4 o = { (__bf16)v.x, (__bf16)v.y, (__bf16)v.z, (__bf16)v.w };
    *(bf16x4*)(xb + 4 * i) = o;
}

// W [C][K][N] f32 -> Wt [C][N][K] bf16 (64x64 LDS-tiled transpose)
template <int WHICH>
__global__ __launch_bounds__(256)
void transpose_kernel(const float* __restrict__ W, __bf16* __restrict__ Wt,
                      const int K, const int N) {
    __shared__ float tile[64][65];
    const int c = blockIdx.z;
    const float* Wc = W + (size_t)c * K * N;
    __bf16* Wtc = Wt + (size_t)c * N * K;
    const int k0 = blockIdx.y * 64, n0 = blockIdx.x * 64;
    const int t = threadIdx.x;
    const int cl = (t & 15) * 4, rw = t >> 4;
#pragma unroll
    for (int p = 0; p < 4; ++p) {
        const int r = rw + p * 16;
        const float4 v = *(const float4*)(Wc + (size_t)(k0 + r) * N + (n0 + cl));
        tile[r][cl]     = v.x;
        tile[r][cl + 1] = v.y;
        tile[r][cl + 2] = v.z;
        tile[r][cl + 3] = v.w;
    }
    __syncthreads();
    const int n = t >> 2, ks = (t & 3) * 16;
    bf16x8 o0, o1;
#pragma unroll
    for (int i = 0; i < 8; ++i) o0[i] = (__bf16)tile[ks + i][n];
#pragma unroll
    for (int i = 0; i < 8; ++i) o1[i] = (__bf16)tile[ks + 8 + i][n];
    __bf16* dst = Wtc + (size_t)(n0 + n) * K + (k0 + ks);
    *(bf16x8*)dst = o0;
    *(bf16x8*)(dst + 8) = o1;
}

// ---------------- category-grouped 128x256 GEMM (m97 structure, 8 waves) ----------------
// A: [NTOK][K] bf16 row-major. Bt: [C][HID][K] bf16. 2 same-category batches
// per m-tile (128 rows). BN=256 (4 n-tiles: halves A re-fetch vs BN=128).
// XCD-aware bijective swizzle (NWG = 528 = 8*66): each XCD gets ~17 contiguous
// category-sorted m-tiles x all 4 n-panels -> B panels L2-resident per XCD.
// 8 waves (2m x 4n), each 64x64 (4x4 of 16x16x32 MFMA). Single-buffered 48 KB
// LDS, 2-barrier K-loop, global_load_lds width-16. 2 blocks/CU.
// EPI: 0 = +bias, relu, +pe -> bf16 ; 1 = +bias, relu -> bf16 ; 2 = +bias -> f32
template <int K, int EPI>
__device__ __forceinline__ void gemm_body(
        const __bf16* __restrict__ A, const __bf16* __restrict__ Bt,
        const float* __restrict__ bias, const float* __restrict__ pe,
        const int* __restrict__ meta,
        __bf16* __restrict__ hout, float* __restrict__ fout) {
    __shared__ __bf16 Ab[128 * 64];    // 16 KB
    __shared__ __bf16 Bb[256 * 64];    // 32 KB
    const int tid = threadIdx.x;       // 0..511
    const int lane = tid & 63;
    const int wv = tid >> 6;           // 0..7
    const int wm = wv >> 2, wn = wv & 3;
    // T1 bijective XCD swizzle: 528 blocks = 8 XCDs * 66
    const int orig = blockIdx.x;
    const int wgid = (orig & 7) * 66 + (orig >> 3);
    const int mt = wgid >> 2;
    const int n0 = (wgid & 3) * 256;
    if (mt >= meta[736]) return;
    const int b0  = meta[256 + mt];
    const int b1  = meta[416 + mt];
    const int cid = meta[576 + mt];
    const int bb  = (b1 < 0) ? b0 : b1;

    const char* Ag0 = (const char*)(A + (size_t)b0 * HSEQ * K);
    const char* Ag1 = (const char*)(A + (size_t)bb * HSEQ * K);
    const char* Bg  = (const char*)(Bt + ((size_t)cid * HID + n0) * K);

    // staging: row = 128 B (64 bf16) = 8 threads x 16 B; 512 thr -> 64 rows/issue
    const int srow = tid >> 3;          // 0..63
    const int scol = (tid & 7) * 16;    // byte within 128 B row-slice

    auto stage = [&](int k0) {
        const size_t kb = (size_t)k0 * 2;
        // A tile: 128 rows (64 from b0, 64 from b1) -> 2 issues
        async16(Ag0 + (size_t)srow * (K * 2) + kb + scol, (char*)Ab + tid * 16);
        async16(Ag1 + (size_t)srow * (K * 2) + kb + scol, (char*)Ab + 8192 + tid * 16);
        // B tile: 256 rows -> 4 issues
#pragma unroll
        for (int j = 0; j < 4; ++j) {
            const int row = j * 64 + srow;
            async16(Bg + (size_t)row * (K * 2) + kb + scol,
                    (char*)Bb + j * 8192 + tid * 16);
        }
    };

    f32x4 acc[4][4] = {};
    const int lr = lane & 15, lh = lane >> 4;

    const int NT = K / 64;
    for (int t = 0; t < NT; ++t) {
        stage(t * 64);
        __syncthreads();               // vmcnt(0) drain: tile staged
#pragma unroll
        for (int kk = 0; kk < 2; ++kk) {
            bf16x8 af[4], bfr[4];
#pragma unroll
            for (int mi = 0; mi < 4; ++mi)
                af[mi] = *(const bf16x8*)&Ab[(wm * 64 + mi * 16 + lr) * 64 + kk * 32 + lh * 8];
#pragma unroll
            for (int ni = 0; ni < 4; ++ni)
                bfr[ni] = *(const bf16x8*)&Bb[(wn * 64 + ni * 16 + lr) * 64 + kk * 32 + lh * 8];
#pragma unroll
            for (int mi = 0; mi < 4; ++mi)
#pragma unroll
                for (int ni = 0; ni < 4; ++ni)
                    acc[mi][ni] = __builtin_amdgcn_mfma_f32_16x16x32_bf16(
                        af[mi], bfr[ni], acc[mi][ni], 0, 0, 0);
        }
        __syncthreads();               // all reads done before restage
    }

    // epilogue: C/D layout col = lane&15, row = (lane>>4)*4 + r
    const bool doStore = (wm == 0) || (b1 >= 0);
    if (!doStore) return;
    const int batch = wm ? b1 : b0;
    const int colg = lane & 15;
    const int row4 = (lane >> 4) * 4;
#pragma unroll
    for (int ni = 0; ni < 4; ++ni) {
        const int n = n0 + wn * 64 + ni * 16 + colg;
        const float bv = bias[cid * HID + n];
#pragma unroll
        for (int mi = 0; mi < 4; ++mi) {
#pragma unroll
            for (int r = 0; r < 4; ++r) {
                const int tok = mi * 16 + row4 + r;   // token within batch = PE index
                const size_t gi = ((size_t)batch * HSEQ + tok) * HID + n;
                float v = acc[mi][ni][r] + bv;
                if constexpr (EPI == 0) {
                    v = fmaxf(v, 0.f) + pe[tok * HID + n];
                    hout[gi] = (__bf16)v;
                } else if constexpr (EPI == 1) {
                    v = fmaxf(v, 0.f);
                    hout[gi] = (__bf16)v;
                } else {
                    fout[gi] = v;
                }
            }
        }
    }
}

// Distinct names per layer so rocprof rows are attributable.
__global__ __launch_bounds__(512, 4)
void gemm_l1(const __bf16* __restrict__ A, const __bf16* __restrict__ Bt,
             const float* __restrict__ bias, const float* __restrict__ pe,
             const int* __restrict__ meta, __bf16* __restrict__ hout) {
    gemm_body<DIN, 0>(A, Bt, bias, pe, meta, hout, nullptr);
}
__global__ __launch_bounds__(512, 4)
void gemm_l2(const __bf16* __restrict__ A, const __bf16* __restrict__ Bt,
             const float* __restrict__ bias,
             const int* __restrict__ meta, __bf16* __restrict__ hout) {
    gemm_body<HID, 1>(A, Bt, bias, nullptr, meta, hout, nullptr);
}
__global__ __launch_bounds__(512, 4)
void gemm_l3(const __bf16* __restrict__ A, const __bf16* __restrict__ Bt,
             const float* __restrict__ bias,
             const int* __restrict__ meta, float* __restrict__ fout) {
    gemm_body<HID, 2>(A, Bt, bias, nullptr, meta, nullptr, fout);
}

// ---------------- launcher ----------------

extern "C" void kernel_launch(void* const* d_in, const int* in_sizes, int n_in,
                              void* d_out, int out_size, void* d_ws, size_t ws_size,
                              hipStream_t stream) {
    (void)in_sizes; (void)n_in; (void)out_size; (void)ws_size;
    const float* x   = (const float*)d_in[0];
    const int*   cat = (const int*)d_in[1];
    const float* W1  = (const float*)d_in[2];
    const float* b1  = (const float*)d_in[3];
    const float* W2  = (const float*)d_in[4];
    const float* b2  = (const float*)d_in[5];
    const float* W3  = (const float*)d_in[6];
    const float* b3  = (const float*)d_in[7];
    float* out = (float*)d_out;

    // Workspace layout (67.1 MB; xb/W1t/pe are dead after L1 and time-alias h2):
    char* ws = (char*)d_ws;
    int*    meta = (int*)ws;                             // [0, 8192)
    __bf16* xb   = (__bf16*)(ws + 8192);                 // 2 MB   (L1 only)
    __bf16* W1t  = (__bf16*)(ws + 8192 + 2097152);       // 1 MB   (L1 only)
    float*  pe   = (float*) (ws + 8192 + 3145728);       // 256 KB (L1 only)
    __bf16* h2   = (__bf16*)(ws + 8192);                 // 32 MB  (written in L2; aliases the above)
    __bf16* W2t  = (__bf16*)(ws + 33562624);             // 16 MB
    __bf16* W3t  = (__bf16*)(ws + 50339840);             // 16 MB
    // h1 (bf16, 32 MB) lives in the first half of d_out (f32 64 MB);
    // fully consumed by L2 before L3 overwrites d_out.
    __bf16* h1 = (__bf16*)d_out;

    setup_kernel<<<dim3(1), dim3(NBATCH), 0, stream>>>(cat, meta);
    pe_kernel<<<dim3(HSEQ), dim3(512), 0, stream>>>(pe);
    cvt_x_kernel<<<dim3(NTOK * DIN / 4 / 256), dim3(256), 0, stream>>>(x, xb);
    transpose_kernel<1><<<dim3(16, 1, NCAT),  dim3(256), 0, stream>>>(W1, W1t, DIN, HID);
    transpose_kernel<2><<<dim3(16, 16, NCAT), dim3(256), 0, stream>>>(W2, W2t, HID, HID);
    transpose_kernel<3><<<dim3(16, 16, NCAT), dim3(256), 0, stream>>>(W3, W3t, HID, HID);

    gemm_l1<<<dim3(NWG), dim3(512), 0, stream>>>(xb, W1t, b1, pe, meta, h1);
    gemm_l2<<<dim3(NWG), dim3(512), 0, stream>>>(h1, W2t, b2, meta, h2);
    gemm_l3<<<dim3(NWG), dim3(512), 0, stream>>>(h2, W3t, b3, meta, out);
}

// Round 4
// 218.326 us; speedup vs baseline: 1.0234x; 1.0234x over previous
//
#include <hip/hip_runtime.h>
#include <hip/hip_bf16.h>
#include <cstdint>
#include <cstddef>

// Problem constants (fixed by the reference)
#define NCAT   8
#define DIN    64
#define HID    1024
#define NBATCH 256
#define HSEQ   64
#define NTOK   (NBATCH * HSEQ)   // 16384
#define MAXTILES 132             // sum ceil(nb_c/2) <= 128 + 4
#define NWG (4 * MAXTILES)       // 528 = 8 * 66 (clean XCD swizzle, r=0)

typedef __bf16 bf16x8 __attribute__((ext_vector_type(8)));
typedef __bf16 bf16x4 __attribute__((ext_vector_type(4)));
typedef float  f32x4  __attribute__((ext_vector_type(4)));

__device__ __forceinline__ void async16(const void* g, void* l) {
    __builtin_amdgcn_global_load_lds(
        (const __attribute__((address_space(1))) unsigned int*)g,
        (__attribute__((address_space(3))) unsigned int*)l,
        16, 0, 0);
}

#define SBAR() asm volatile("s_barrier" ::: "memory")

// ---------------- setup: counting-sort batches by category, build tile table ----------------
// meta layout (ints): order[256] @0, tileB0[160] @256, tileB1[160] @416,
//                     tileCat[160] @576, ntiles @736
__global__ void setup_kernel(const int* __restrict__ cat, int* __restrict__ meta) {
    __shared__ int scat[NBATCH];
    __shared__ int cnt[NCAT], pfx[NCAT + 1];
    const int tid = threadIdx.x;
    const int c = cat[tid];
    scat[tid] = c;
    if (tid < NCAT) cnt[tid] = 0;
    __syncthreads();
    atomicAdd(&cnt[c], 1);
    __syncthreads();
    if (tid == 0) {
        pfx[0] = 0;
        for (int i = 0; i < NCAT; ++i) pfx[i + 1] = pfx[i] + cnt[i];
    }
    __syncthreads();
    int r = 0;
    for (int b = 0; b < tid; ++b) r += (scat[b] == c);
    meta[pfx[c] + r] = tid;                 // order[]
    __threadfence();
    __syncthreads();
    if (tid == 0) {
        int nt = 0;
        for (int cc = 0; cc < NCAT; ++cc) {
            const int base = pfx[cc], n = cnt[cc];
            for (int j = 0; j < n; j += 2) {
                meta[256 + nt] = meta[base + j];                        // tileB0
                meta[416 + nt] = (j + 1 < n) ? meta[base + j + 1] : -1; // tileB1
                meta[576 + nt] = cc;                                    // tileCat
                ++nt;
            }
        }
        meta[736] = nt;
    }
}

// ---------------- prep kernels ----------------

__global__ void pe_kernel(float* __restrict__ pe) {
    const int t = blockIdx.x;        // 0..63
    const int i = threadIdx.x;       // 0..511
    const float div = expf((float)(2 * i) * (-9.210340371976184f / 1024.f));
    const float a = (float)t * div;
    pe[t * HID + 2 * i]     = sinf(a);
    pe[t * HID + 2 * i + 1] = cosf(a);
}

__global__ void cvt_x_kernel(const float* __restrict__ x, __bf16* __restrict__ xb) {
    const size_t i = (size_t)blockIdx.x * blockDim.x + threadIdx.x;
    const float4 v = ((const float4*)x)[i];
    bf16x4 o = { (__bf16)v.x, (__bf16)v.y, (__bf16)v.z, (__bf16)v.w };
    *(bf16x4*)(xb + 4 * i) = o;
}

// W [C][K][N] f32 -> Wt [C][N][K] bf16 (64x64 LDS-tiled transpose)
template <int WHICH>
__global__ __launch_bounds__(256)
void transpose_kernel(const float* __restrict__ W, __bf16* __restrict__ Wt,
                      const int K, const int N) {
    __shared__ float tile[64][65];
    const int c = blockIdx.z;
    const float* Wc = W + (size_t)c * K * N;
    __bf16* Wtc = Wt + (size_t)c * N * K;
    const int k0 = blockIdx.y * 64, n0 = blockIdx.x * 64;
    const int t = threadIdx.x;
    const int cl = (t & 15) * 4, rw = t >> 4;
#pragma unroll
    for (int p = 0; p < 4; ++p) {
        const int r = rw + p * 16;
        const float4 v = *(const float4*)(Wc + (size_t)(k0 + r) * N + (n0 + cl));
        tile[r][cl]     = v.x;
        tile[r][cl + 1] = v.y;
        tile[r][cl + 2] = v.z;
        tile[r][cl + 3] = v.w;
    }
    __syncthreads();
    const int n = t >> 2, ks = (t & 3) * 16;
    bf16x8 o0, o1;
#pragma unroll
    for (int i = 0; i < 8; ++i) o0[i] = (__bf16)tile[ks + i][n];
#pragma unroll
    for (int i = 0; i < 8; ++i) o1[i] = (__bf16)tile[ks + 8 + i][n];
    __bf16* dst = Wtc + (size_t)(n0 + n) * K + (k0 + ks);
    *(bf16x8*)dst = o0;
    *(bf16x8*)(dst + 8) = o1;
}

// ---------------- category-grouped 128x256 GEMM, counted-vmcnt dbuf ----------------
// A: [NTOK][K] bf16 row-major. Bt: [C][HID][K] bf16. 2 same-category batches
// per m-tile (128 rows). BN=256. XCD-aware bijective swizzle (528 = 8*66).
// 8 waves (2m x 4n), each 64x64 (4x4 of 16x16x32 MFMA).
// Double-buffered 96 KB LDS; issue-early stage; s_waitcnt vmcnt(6) (counted,
// never 0 mid-loop, T4) at a raw s_barrier; T2 slot-XOR swizzle applied to the
// GLOBAL source (LDS dest stays linear per global_load_lds HW) and to the
// ds_read address (same involution); T5 setprio around MFMA clusters.
// EPI: 0 = +bias, relu, +pe -> bf16 ; 1 = +bias, relu -> bf16 ; 2 = +bias -> f32
template <int K, int EPI>
__device__ __forceinline__ void gemm_body(
        const __bf16* __restrict__ A, const __bf16* __restrict__ Bt,
        const float* __restrict__ bias, const float* __restrict__ pe,
        const int* __restrict__ meta,
        __bf16* __restrict__ hout, float* __restrict__ fout) {
    __shared__ __bf16 Ab[2][128 * 64];    // 2 x 16 KB
    __shared__ __bf16 Bb[2][256 * 64];    // 2 x 32 KB
    const int tid = threadIdx.x;       // 0..511
    const int lane = tid & 63;
    const int wv = tid >> 6;           // 0..7
    const int wm = wv >> 2, wn = wv & 3;
    // T1 bijective XCD swizzle: 528 blocks = 8 XCDs * 66
    const int orig = blockIdx.x;
    const int wgid = (orig & 7) * 66 + (orig >> 3);
    const int mt = wgid >> 2;
    const int n0 = (wgid & 3) * 256;
    if (mt >= meta[736]) return;       // block-uniform: safe before barriers
    const int b0  = meta[256 + mt];
    const int b1  = meta[416 + mt];
    const int cid = meta[576 + mt];
    const int bb  = (b1 < 0) ? b0 : b1;

    const char* Ag0 = (const char*)(A + (size_t)b0 * HSEQ * K);
    const char* Ag1 = (const char*)(A + (size_t)bb * HSEQ * K);
    const char* Bg  = (const char*)(Bt + ((size_t)cid * HID + n0) * K);

    // staging: row = 128 B (64 bf16) = 8 threads x 16 B; 512 thr -> 64 rows/issue
    const int srow = tid >> 3;          // 0..63
    // T2: source slot pre-swizzle; LDS dest linear (slot s holds global slot s^(row&7))
    const int scol_sw = (((tid & 7) ^ (srow & 7)) * 16);

    auto stage = [&](int buf, int k0) {
        const size_t kb = (size_t)k0 * 2;
        // A tile: 128 rows (64 from b0, 64 from b1) -> 2 issues
        async16(Ag0 + (size_t)srow * (K * 2) + kb + scol_sw, (char*)&Ab[buf][0] + tid * 16);
        async16(Ag1 + (size_t)srow * (K * 2) + kb + scol_sw, (char*)&Ab[buf][0] + 8192 + tid * 16);
        // B tile: 256 rows -> 4 issues
#pragma unroll
        for (int j = 0; j < 4; ++j) {
            const int row = j * 64 + srow;
            async16(Bg + (size_t)row * (K * 2) + kb + scol_sw,
                    (char*)&Bb[buf][0] + j * 8192 + tid * 16);
        }
    };

    f32x4 acc[4][4] = {};
    const int lr = lane & 15, lh = lane >> 4;
    const int rsw = lr & 7;            // row&7 for all fragment rows (rows = x*8(+16..)+lr)

    const int NT = K / 64;
    stage(0, 0);
    for (int t = 0; t < NT; ++t) {
        if (t + 1 < NT) {
            stage((t + 1) & 1, (t + 1) * 64);
            asm volatile("s_waitcnt vmcnt(6)" ::: "memory");  // own tile-t loads done
        } else {
            asm volatile("s_waitcnt vmcnt(0)" ::: "memory");
        }
        __builtin_amdgcn_sched_barrier(0);
        SBAR();                         // all waves' tile-t loads complete
        __builtin_amdgcn_sched_barrier(0);
        const char* Abase = (const char*)&Ab[t & 1][0];
        const char* Bbase = (const char*)&Bb[t & 1][0];
#pragma unroll
        for (int kk = 0; kk < 2; ++kk) {
            bf16x8 af[4], bfr[4];
            // slot wanted = kk*4+lh; swizzled slot = wanted ^ (row&7), row&7 == lr&7
            const int soff = ((((kk << 2) | lh) ^ rsw) << 4);
#pragma unroll
            for (int mi = 0; mi < 4; ++mi) {
                const int row = wm * 64 + mi * 16 + lr;
                af[mi] = *(const bf16x8*)(Abase + row * 128 + soff);
            }
#pragma unroll
            for (int ni = 0; ni < 4; ++ni) {
                const int row = wn * 64 + ni * 16 + lr;
                bfr[ni] = *(const bf16x8*)(Bbase + row * 128 + soff);
            }
            __builtin_amdgcn_s_setprio(1);
#pragma unroll
            for (int mi = 0; mi < 4; ++mi)
#pragma unroll
                for (int ni = 0; ni < 4; ++ni)
                    acc[mi][ni] = __builtin_amdgcn_mfma_f32_16x16x32_bf16(
                        af[mi], bfr[ni], acc[mi][ni], 0, 0, 0);
            __builtin_amdgcn_s_setprio(0);
        }
        __builtin_amdgcn_sched_barrier(0);
        SBAR();                         // all reads of buf[t&1] done before restage
        __builtin_amdgcn_sched_barrier(0);
    }

    // epilogue: C/D layout col = lane&15, row = (lane>>4)*4 + r
    const bool doStore = (wm == 0) || (b1 >= 0);
    if (!doStore) return;
    const int batch = wm ? b1 : b0;
    const int colg = lane & 15;
    const int row4 = (lane >> 4) * 4;
#pragma unroll
    for (int ni = 0; ni < 4; ++ni) {
        const int n = n0 + wn * 64 + ni * 16 + colg;
        const float bv = bias[cid * HID + n];
#pragma unroll
        for (int mi = 0; mi < 4; ++mi) {
#pragma unroll
            for (int r = 0; r < 4; ++r) {
                const int tok = mi * 16 + row4 + r;   // token within batch = PE index
                const size_t gi = ((size_t)batch * HSEQ + tok) * HID + n;
                float v = acc[mi][ni][r] + bv;
                if constexpr (EPI == 0) {
                    v = fmaxf(v, 0.f) + pe[tok * HID + n];
                    hout[gi] = (__bf16)v;
                } else if constexpr (EPI == 1) {
                    v = fmaxf(v, 0.f);
                    hout[gi] = (__bf16)v;
                } else {
                    fout[gi] = v;
                }
            }
        }
    }
}

// Distinct names per layer so rocprof rows are attributable.
__global__ __launch_bounds__(512, 2)
void gemm_l1(const __bf16* __restrict__ A, const __bf16* __restrict__ Bt,
             const float* __restrict__ bias, const float* __restrict__ pe,
             const int* __restrict__ meta, __bf16* __restrict__ hout) {
    gemm_body<DIN, 0>(A, Bt, bias, pe, meta, hout, nullptr);
}
__global__ __launch_bounds__(512, 2)
void gemm_l2(const __bf16* __restrict__ A, const __bf16* __restrict__ Bt,
             const float* __restrict__ bias,
             const int* __restrict__ meta, __bf16* __restrict__ hout) {
    gemm_body<HID, 1>(A, Bt, bias, nullptr, meta, hout, nullptr);
}
__global__ __launch_bounds__(512, 2)
void gemm_l3(const __bf16* __restrict__ A, const __bf16* __restrict__ Bt,
             const float* __restrict__ bias,
             const int* __restrict__ meta, float* __restrict__ fout) {
    gemm_body<HID, 2>(A, Bt, bias, nullptr, meta, nullptr, fout);
}

// ---------------- launcher ----------------

extern "C" void kernel_launch(void* const* d_in, const int* in_sizes, int n_in,
                              void* d_out, int out_size, void* d_ws, size_t ws_size,
                              hipStream_t stream) {
    (void)in_sizes; (void)n_in; (void)out_size; (void)ws_size;
    const float* x   = (const float*)d_in[0];
    const int*   cat = (const int*)d_in[1];
    const float* W1  = (const float*)d_in[2];
    const float* b1  = (const float*)d_in[3];
    const float* W2  = (const float*)d_in[4];
    const float* b2  = (const float*)d_in[5];
    const float* W3  = (const float*)d_in[6];
    const float* b3  = (const float*)d_in[7];
    float* out = (float*)d_out;

    // Workspace layout (67.1 MB; xb/W1t/pe are dead after L1 and time-alias h2):
    char* ws = (char*)d_ws;
    int*    meta = (int*)ws;                             // [0, 8192)
    __bf16* xb   = (__bf16*)(ws + 8192);                 // 2 MB   (L1 only)
    __bf16* W1t  = (__bf16*)(ws + 8192 + 2097152);       // 1 MB   (L1 only)
    float*  pe   = (float*) (ws + 8192 + 3145728);       // 256 KB (L1 only)
    __bf16* h2   = (__bf16*)(ws + 8192);                 // 32 MB  (written in L2; aliases the above)
    __bf16* W2t  = (__bf16*)(ws + 33562624);             // 16 MB
    __bf16* W3t  = (__bf16*)(ws + 50339840);             // 16 MB
    // h1 (bf16, 32 MB) lives in the first half of d_out (f32 64 MB);
    // fully consumed by L2 before L3 overwrites d_out.
    __bf16* h1 = (__bf16*)d_out;

    setup_kernel<<<dim3(1), dim3(NBATCH), 0, stream>>>(cat, meta);
    pe_kernel<<<dim3(HSEQ), dim3(512), 0, stream>>>(pe);
    cvt_x_kernel<<<dim3(NTOK * DIN / 4 / 256), dim3(256), 0, stream>>>(x, xb);
    transpose_kernel<1><<<dim3(16, 1, NCAT),  dim3(256), 0, stream>>>(W1, W1t, DIN, HID);
    transpose_kernel<2><<<dim3(16, 16, NCAT), dim3(256), 0, stream>>>(W2, W2t, HID, HID);
    transpose_kernel<3><<<dim3(16, 16, NCAT), dim3(256), 0, stream>>>(W3, W3t, HID, HID);

    gemm_l1<<<dim3(NWG), dim3(512), 0, stream>>>(xb, W1t, b1, pe, meta, h1);
    gemm_l2<<<dim3(NWG), dim3(512), 0, stream>>>(h1, W2t, b2, meta, h2);
    gemm_l3<<<dim3(NWG), dim3(512), 0, stream>>>(h2, W3t, b3, meta, out);
}